// Round 1
// baseline (596.550 us; speedup 1.0000x reference)
//
#include <hip/hip_runtime.h>

// GCN 2-layer: h = relu(Ahat @ (x @ W) + b), twice.
// Ahat = Dinv^0.5 (A + I) Dinv^0.5 with in-degree (incl self-loop) normalization.
// Strategy: build CSR-by-dst once per call (ws is re-poisoned), fp32 LDS-tiled
// GEMM with dinv-scaled epilogue, wave-per-node gather aggregation (no fp32 atomics).

#define NFEAT 128

// ---------------- utility ----------------
__global__ __launch_bounds__(256) void k_zero_i32(int* __restrict__ p, int n) {
    int i = blockIdx.x * 256 + threadIdx.x;
    if (i < n) p[i] = 0;
}

__global__ __launch_bounds__(256) void k_count(const int* __restrict__ dst,
                                               int* __restrict__ counts, int E) {
    int e = blockIdx.x * 256 + threadIdx.x;
    if (e < E) atomicAdd(&counts[dst[e]], 1);
}

// ---------------- scan (counts -> row_ptr exclusive) ----------------
// scan1: each block scans 1024 elements (256 thr x 4), writes local-exclusive
// results to row_ptr and its block total to bsums.
__global__ __launch_bounds__(256) void k_scan1(const int* __restrict__ counts,
                                               int* __restrict__ row_ptr,
                                               int* __restrict__ bsums, int N) {
    __shared__ int sdata[256];
    int tid = threadIdx.x;
    int base = blockIdx.x * 1024 + tid * 4;
    int v[4];
#pragma unroll
    for (int j = 0; j < 4; j++) v[j] = (base + j < N) ? counts[base + j] : 0;
    int tsum = v[0] + v[1] + v[2] + v[3];
    sdata[tid] = tsum;
    __syncthreads();
    for (int off = 1; off < 256; off <<= 1) {
        int add = (tid >= off) ? sdata[tid - off] : 0;
        __syncthreads();
        sdata[tid] += add;
        __syncthreads();
    }
    int run = sdata[tid] - tsum;  // exclusive prefix of this thread's chunk
#pragma unroll
    for (int j = 0; j < 4; j++) {
        if (base + j < N) row_ptr[base + j] = run;
        run += v[j];
    }
    if (tid == 255) bsums[blockIdx.x] = sdata[255];
}

// scan2: single block exclusive-scans the (<=128) block sums in place.
__global__ __launch_bounds__(128) void k_scan2(int* __restrict__ bsums, int nb) {
    __shared__ int sdata[128];
    int tid = threadIdx.x;
    int val = (tid < nb) ? bsums[tid] : 0;
    sdata[tid] = val;
    __syncthreads();
    for (int off = 1; off < 128; off <<= 1) {
        int add = (tid >= off) ? sdata[tid - off] : 0;
        __syncthreads();
        sdata[tid] += add;
        __syncthreads();
    }
    if (tid < nb) bsums[tid] = sdata[tid] - val;
}

// scan3: add block offsets; compute dinv = rsqrt(deg+1); reset counts (cursor).
__global__ __launch_bounds__(256) void k_scan3(int* __restrict__ row_ptr,
                                               const int* __restrict__ bsums,
                                               int* __restrict__ counts,
                                               float* __restrict__ dinv, int N, int E) {
    int i = blockIdx.x * 256 + threadIdx.x;
    if (i < N) {
        row_ptr[i] += bsums[i >> 10];
        dinv[i] = rsqrtf((float)(counts[i] + 1));  // +1 = self-loop; always > 0
        counts[i] = 0;                             // becomes fill cursor
    }
    if (i == 0) row_ptr[N] = E;
}

__global__ __launch_bounds__(256) void k_fill(const int* __restrict__ src,
                                              const int* __restrict__ dst,
                                              const int* __restrict__ row_ptr,
                                              int* __restrict__ cursor,
                                              int* __restrict__ col, int E) {
    int e = blockIdx.x * 256 + threadIdx.x;
    if (e < E) {
        int d = dst[e];
        int pos = row_ptr[d] + atomicAdd(&cursor[d], 1);
        col[pos] = src[e];
    }
}

// ---------------- GEMM: out[m][n] = dinv[m] * sum_k A[m][k] W[k][n] ----------------
// Block: 128 rows x 128 cols, 256 threads, 8x8 register tile, K-tiles of 32.
__global__ __launch_bounds__(256) void k_gemm_scale(const float* __restrict__ A,
                                                    const float* __restrict__ W,
                                                    const float* __restrict__ dinv,
                                                    float* __restrict__ out, int M) {
    __shared__ float As[32][132];  // transposed: As[k][m], stride 132 kills worst conflicts
    __shared__ float Bs[32][128];  // Bs[k][n]
    int tid = threadIdx.x;
    int m0 = blockIdx.x * 128;
    int rm0 = (tid >> 4) << 3;  // 0..120
    int cn0 = (tid & 15) << 3;  // 0..120
    float acc[8][8];
#pragma unroll
    for (int i = 0; i < 8; i++)
#pragma unroll
        for (int j = 0; j < 8; j++) acc[i][j] = 0.f;

    for (int kt = 0; kt < NFEAT; kt += 32) {
        // Stage A tile (128 rows x 32 k), transposed into LDS.
#pragma unroll
        for (int i = 0; i < 4; i++) {
            int idx = tid + i * 256;   // 0..1023
            int r = idx >> 3;          // 0..127
            int kq = (idx & 7) << 2;   // 0,4,..,28
            int row = m0 + r;
            float4 v = make_float4(0.f, 0.f, 0.f, 0.f);
            if (row < M) v = *(const float4*)(A + (size_t)row * NFEAT + kt + kq);
            As[kq + 0][r] = v.x;
            As[kq + 1][r] = v.y;
            As[kq + 2][r] = v.z;
            As[kq + 3][r] = v.w;
        }
        // Stage B tile (32 k x 128 n), straight copy.
#pragma unroll
        for (int i = 0; i < 4; i++) {
            int idx = tid + i * 256;  // 0..1023
            int kr = idx >> 5;        // 0..31
            int nc = (idx & 31) << 2; // 0..124
            *(float4*)&Bs[kr][nc] = *(const float4*)(W + (size_t)(kt + kr) * NFEAT + nc);
        }
        __syncthreads();
#pragma unroll
        for (int k = 0; k < 32; k++) {
            float a[8], b[8];
            *(float4*)&a[0] = *(float4*)&As[k][rm0];
            *(float4*)&a[4] = *(float4*)&As[k][rm0 + 4];
            *(float4*)&b[0] = *(float4*)&Bs[k][cn0];
            *(float4*)&b[4] = *(float4*)&Bs[k][cn0 + 4];
#pragma unroll
            for (int i = 0; i < 8; i++)
#pragma unroll
                for (int j = 0; j < 8; j++) acc[i][j] += a[i] * b[j];
        }
        __syncthreads();
    }
#pragma unroll
    for (int i = 0; i < 8; i++) {
        int row = m0 + rm0 + i;
        if (row < M) {
            float d = dinv[row];
            float4 o0 = make_float4(acc[i][0] * d, acc[i][1] * d, acc[i][2] * d, acc[i][3] * d);
            float4 o1 = make_float4(acc[i][4] * d, acc[i][5] * d, acc[i][6] * d, acc[i][7] * d);
            *(float4*)(out + (size_t)row * NFEAT + cn0) = o0;
            *(float4*)(out + (size_t)row * NFEAT + cn0 + 4) = o1;
        }
    }
}

// ---------------- Aggregation: wave per node ----------------
// out[i] = relu( dinv[i] * (hs[i] + sum_{e: dst=i} hs[src_e]) + bias )
// hs rows are pre-scaled by dinv[src] in the GEMM epilogue; hs[i] term = self-loop.
__global__ __launch_bounds__(256) void k_aggregate(const float* __restrict__ hs,
                                                   const int* __restrict__ row_ptr,
                                                   const int* __restrict__ col,
                                                   const float* __restrict__ dinv,
                                                   const float* __restrict__ bias,
                                                   float* __restrict__ out, int N) {
    int wave = blockIdx.x * 4 + (threadIdx.x >> 6);
    int lane = threadIdx.x & 63;
    if (wave >= N) return;
    int i = wave;
    const float2* hs2 = (const float2*)hs;
    float2 acc = hs2[(size_t)i * 64 + lane];  // self-loop contribution
    int s = row_ptr[i];
    int e = row_ptr[i + 1];
    int k = s;
    for (; k + 4 <= e; k += 4) {
        int s0 = col[k], s1 = col[k + 1], s2 = col[k + 2], s3 = col[k + 3];
        float2 a = hs2[(size_t)s0 * 64 + lane];
        float2 b = hs2[(size_t)s1 * 64 + lane];
        float2 c = hs2[(size_t)s2 * 64 + lane];
        float2 d = hs2[(size_t)s3 * 64 + lane];
        acc.x += (a.x + b.x) + (c.x + d.x);
        acc.y += (a.y + b.y) + (c.y + d.y);
    }
    for (; k < e; ++k) {
        float2 a = hs2[(size_t)col[k] * 64 + lane];
        acc.x += a.x;
        acc.y += a.y;
    }
    float di = dinv[i];
    float2 bv = ((const float2*)bias)[lane];
    float ox = fmaxf(fmaf(di, acc.x, bv.x), 0.f);
    float oy = fmaxf(fmaf(di, acc.y, bv.y), 0.f);
    float2 o;
    o.x = ox;
    o.y = oy;
    ((float2*)out)[(size_t)i * 64 + lane] = o;
}

// ---------------- launch ----------------
extern "C" void kernel_launch(void* const* d_in, const int* in_sizes, int n_in,
                              void* d_out, int out_size, void* d_ws, size_t ws_size,
                              hipStream_t stream) {
    const float* x  = (const float*)d_in[0];
    const int*   ei = (const int*)d_in[1];
    const float* W1 = (const float*)d_in[2];
    const float* b1 = (const float*)d_in[3];
    const float* W2 = (const float*)d_in[4];
    const float* b2 = (const float*)d_in[5];
    float* out = (float*)d_out;

    const int N = in_sizes[0] / NFEAT;   // 100000
    const int E = in_sizes[1] / 2;       // 1600000
    const int* src = ei;
    const int* dst = ei + E;

    // Workspace carve (512B-aligned slots).
    char* w = (char*)d_ws;
    size_t off = 0;
    auto alloc = [&](size_t bytes) -> void* {
        void* p = w + off;
        off = (off + bytes + 511) & ~(size_t)511;
        return p;
    };
    float* hs      = (float*)alloc((size_t)N * NFEAT * 4);  // scaled transform
    float* y1      = (float*)alloc((size_t)N * NFEAT * 4);  // layer-1 output
    int*   counts  = (int*)alloc((size_t)N * 4);            // degree, then cursor
    int*   row_ptr = (int*)alloc((size_t)(N + 1) * 4);
    float* dinv    = (float*)alloc((size_t)N * 4);
    int*   col     = (int*)alloc((size_t)E * 4);
    int*   bsums   = (int*)alloc(1024 * 4);
    (void)ws_size; (void)n_in; (void)out_size;

    const int nblkN = (N + 255) / 256;      // 391
    const int nblkE = (E + 255) / 256;      // 6250
    const int nscan = (N + 1023) / 1024;    // 98

    // 1) degrees
    k_zero_i32<<<nblkN, 256, 0, stream>>>(counts, N);
    k_count<<<nblkE, 256, 0, stream>>>(dst, counts, E);
    // 2) CSR
    k_scan1<<<nscan, 256, 0, stream>>>(counts, row_ptr, bsums, N);
    k_scan2<<<1, 128, 0, stream>>>(bsums, nscan);
    k_scan3<<<nblkN, 256, 0, stream>>>(row_ptr, bsums, counts, dinv, N, E);
    k_fill<<<nblkE, 256, 0, stream>>>(src, dst, row_ptr, counts, col, E);

    const int gemmBlk = (N + 127) / 128;    // 782
    const int aggBlk  = (N + 3) / 4;        // 25000

    // Layer 1
    k_gemm_scale<<<gemmBlk, 256, 0, stream>>>(x, W1, dinv, hs, N);
    k_aggregate<<<aggBlk, 256, 0, stream>>>(hs, row_ptr, col, dinv, b1, y1, N);
    // Layer 2
    k_gemm_scale<<<gemmBlk, 256, 0, stream>>>(y1, W2, dinv, hs, N);
    k_aggregate<<<aggBlk, 256, 0, stream>>>(hs, row_ptr, col, dinv, b2, out, N);
}

// Round 2
// 480.473 us; speedup vs baseline: 1.2416x; 1.2416x over previous
//
#include <hip/hip_runtime.h>

// GCN 2-layer: h = relu(Ahat @ (x @ W) + b), twice.
// Round 2: bf16 everywhere in the middle (MFMA GEMM + bf16 gather messages),
// fp32 accumulation and fp32 final output. CSR build unchanged.

#define NFEAT 128

typedef __attribute__((ext_vector_type(8))) short s8v;    // 8 bf16 (4 VGPRs) MFMA A/B frag
typedef __attribute__((ext_vector_type(4))) float f4v;    // MFMA C/D frag

// ---- bf16 helpers (rne) ----
__device__ inline ushort f2bf(float f) {
    union { float f; uint u; } x; x.f = f;
    uint u = x.u;
    return (ushort)((u + 0x7fffu + ((u >> 16) & 1u)) >> 16);
}
__device__ inline float bf16lo(uint u) { union { uint u; float f; } x; x.u = u << 16; return x.f; }
__device__ inline float bf16hi(uint u) { union { uint u; float f; } x; x.u = u & 0xffff0000u; return x.f; }

// ---------------- utility ----------------
__global__ __launch_bounds__(256) void k_zero_i32(int* __restrict__ p, int n) {
    int i = blockIdx.x * 256 + threadIdx.x;
    if (i < n) p[i] = 0;
}

__global__ __launch_bounds__(256) void k_count(const int* __restrict__ dst,
                                               int* __restrict__ counts, int E) {
    int e = blockIdx.x * 256 + threadIdx.x;
    if (e < E) atomicAdd(&counts[dst[e]], 1);
}

// ---------------- scan (counts -> row_ptr exclusive) ----------------
__global__ __launch_bounds__(256) void k_scan1(const int* __restrict__ counts,
                                               int* __restrict__ row_ptr,
                                               int* __restrict__ bsums, int N) {
    __shared__ int sdata[256];
    int tid = threadIdx.x;
    int base = blockIdx.x * 1024 + tid * 4;
    int v[4];
#pragma unroll
    for (int j = 0; j < 4; j++) v[j] = (base + j < N) ? counts[base + j] : 0;
    int tsum = v[0] + v[1] + v[2] + v[3];
    sdata[tid] = tsum;
    __syncthreads();
    for (int off = 1; off < 256; off <<= 1) {
        int add = (tid >= off) ? sdata[tid - off] : 0;
        __syncthreads();
        sdata[tid] += add;
        __syncthreads();
    }
    int run = sdata[tid] - tsum;
#pragma unroll
    for (int j = 0; j < 4; j++) {
        if (base + j < N) row_ptr[base + j] = run;
        run += v[j];
    }
    if (tid == 255) bsums[blockIdx.x] = sdata[255];
}

__global__ __launch_bounds__(128) void k_scan2(int* __restrict__ bsums, int nb) {
    __shared__ int sdata[128];
    int tid = threadIdx.x;
    int val = (tid < nb) ? bsums[tid] : 0;
    sdata[tid] = val;
    __syncthreads();
    for (int off = 1; off < 128; off <<= 1) {
        int add = (tid >= off) ? sdata[tid - off] : 0;
        __syncthreads();
        sdata[tid] += add;
        __syncthreads();
    }
    if (tid < nb) bsums[tid] = sdata[tid] - val;
}

__global__ __launch_bounds__(256) void k_scan3(int* __restrict__ row_ptr,
                                               const int* __restrict__ bsums,
                                               int* __restrict__ counts,
                                               float* __restrict__ dinv, int N, int E) {
    int i = blockIdx.x * 256 + threadIdx.x;
    if (i < N) {
        row_ptr[i] += bsums[i >> 10];
        dinv[i] = rsqrtf((float)(counts[i] + 1));
        counts[i] = 0;
    }
    if (i == 0) row_ptr[N] = E;
}

__global__ __launch_bounds__(256) void k_fill(const int* __restrict__ src,
                                              const int* __restrict__ dst,
                                              const int* __restrict__ row_ptr,
                                              int* __restrict__ cursor,
                                              int* __restrict__ col, int E) {
    int e = blockIdx.x * 256 + threadIdx.x;
    if (e < E) {
        int d = dst[e];
        int pos = row_ptr[d] + atomicAdd(&cursor[d], 1);
        col[pos] = src[e];
    }
}

// ---------------- W transpose + bf16 convert (once per call, 2 tiny blocks) ----------------
__global__ __launch_bounds__(256) void k_prep_wt(const float* __restrict__ W1,
                                                 const float* __restrict__ W2,
                                                 ushort* __restrict__ WT1,
                                                 ushort* __restrict__ WT2) {
    __shared__ float Ls[128][133];
    const float* W = blockIdx.x ? W2 : W1;
    ushort* WT = blockIdx.x ? WT2 : WT1;
    int t = threadIdx.x;
#pragma unroll
    for (int i = 0; i < 64; i++) {
        int idx = t + i * 256;
        Ls[idx >> 7][idx & 127] = W[idx];
    }
    __syncthreads();
#pragma unroll
    for (int i = 0; i < 8; i++) {
        int idx = t + i * 256;
        int n = idx >> 4;          // output row (W column)
        int k8 = (idx & 15) << 3;  // 8 k's per thread
        ushort o[8];
#pragma unroll
        for (int j = 0; j < 8; j++) o[j] = f2bf(Ls[k8 + j][n]);
        uint4 pk;
        __builtin_memcpy(&pk, o, 16);
        *(uint4*)&WT[n * 128 + k8] = pk;  // WT[n][k] row-major bf16, coalesced
    }
}

// ---------------- MFMA GEMM: hs[m][n] = bf16( dinv[m] * sum_k A[m][k] W[k][n] ) ----
// Block: 128 rows x 128 cols (full N=K=128), 4 waves, wave w does rows [w*32,w*32+32).
// LDS: As/Bs 128x128 bf16 dense with 16B-chunk XOR swizzle (<=2-way conflicts), 64 KB total.
__device__ inline ushort* lds_chunk(ushort* base, int r, int c) {
    // row r (128 bf16 = 16 chunks of 8), logical chunk c -> physical c ^ (r&15)
    return base + r * 128 + ((c ^ (r & 15)) << 3);
}

template <bool ABF16>
__global__ __launch_bounds__(256) void k_gemm_mfma(const void* __restrict__ Ap,
                                                   const ushort* __restrict__ WT,  // bf16 [n][k]
                                                   const float* __restrict__ dinv,
                                                   ushort* __restrict__ hs,  // bf16 [M][128]
                                                   int M) {
    __shared__ ushort As[128 * 128];
    __shared__ ushort Bs[128 * 128];
    int t = threadIdx.x;
    int m0 = blockIdx.x * 128;

    // stage B: straight copy of WT (already bf16, row-major [n][k])
    {
        const uint4* wt4 = (const uint4*)WT;
#pragma unroll
        for (int i = 0; i < 8; i++) {
            int idx = t + i * 256;
            int n = idx >> 4;
            int c = idx & 15;
            uint4 v = wt4[idx];
            *(uint4*)lds_chunk(Bs, n, c) = v;
        }
    }
    // stage A
    if (ABF16) {
        const ushort* A = (const ushort*)Ap;
#pragma unroll
        for (int i = 0; i < 8; i++) {
            int idx = t + i * 256;
            int r = idx >> 4;
            int c = idx & 15;
            int row = m0 + r;
            uint4 v = make_uint4(0, 0, 0, 0);
            if (row < M) v = *(const uint4*)(A + (size_t)row * NFEAT + (c << 3));
            *(uint4*)lds_chunk(As, r, c) = v;
        }
    } else {
        const float* A = (const float*)Ap;
#pragma unroll
        for (int i = 0; i < 16; i++) {
            int idx = t + i * 256;
            int r = idx >> 5;
            int t5 = idx & 31;      // float4 index within row
            int c = t5 >> 1;        // 16B bf16 chunk
            int h = t5 & 1;         // which 8B half
            int row = m0 + r;
            float4 v = make_float4(0.f, 0.f, 0.f, 0.f);
            if (row < M) v = *(const float4*)(A + (size_t)row * NFEAT + t5 * 4);
            ushort o[4] = {f2bf(v.x), f2bf(v.y), f2bf(v.z), f2bf(v.w)};
            uint2 pk;
            __builtin_memcpy(&pk, o, 8);
            *(uint2*)(lds_chunk(As, r, c) + h * 4) = pk;
        }
    }
    __syncthreads();

    int w = t >> 6, l = t & 63;
    int q = l >> 4, ln = l & 15;
    f4v acc[2][8];
#pragma unroll
    for (int mt = 0; mt < 2; mt++)
#pragma unroll
        for (int nt = 0; nt < 8; nt++) acc[mt][nt] = (f4v){0.f, 0.f, 0.f, 0.f};

#pragma unroll
    for (int ks = 0; ks < 4; ks++) {
        int c = ks * 4 + q;  // 16B chunk holding k = ks*32 + q*8 .. +7
        s8v a0 = *(s8v*)lds_chunk(As, w * 32 + ln, c);
        s8v a1 = *(s8v*)lds_chunk(As, w * 32 + 16 + ln, c);
#pragma unroll
        for (int nt = 0; nt < 8; nt++) {
            s8v b = *(s8v*)lds_chunk(Bs, nt * 16 + ln, c);
            acc[0][nt] = __builtin_amdgcn_mfma_f32_16x16x32_bf16(a0, b, acc[0][nt], 0, 0, 0);
            acc[1][nt] = __builtin_amdgcn_mfma_f32_16x16x32_bf16(a1, b, acc[1][nt], 0, 0, 0);
        }
    }

    // epilogue: C/D layout col=lane&15, row=quad*4+reg (m89/m91-verified)
#pragma unroll
    for (int mt = 0; mt < 2; mt++) {
#pragma unroll
        for (int r = 0; r < 4; r++) {
            int grow = m0 + w * 32 + mt * 16 + q * 4 + r;
            if (grow < M) {
                float d = dinv[grow];
#pragma unroll
                for (int nt = 0; nt < 8; nt++) {
                    hs[(size_t)grow * NFEAT + nt * 16 + ln] = f2bf(acc[mt][nt][r] * d);
                }
            }
        }
    }
}

// ---------------- Aggregation: wave per node, bf16 messages, fp32 accumulate ----
// out[i] = relu( dinv[i] * (hs[i] + sum_{e: dst=i} hs[src_e]) + bias )
template <bool OUT_BF16>
__global__ __launch_bounds__(256) void k_aggregate(const uint* __restrict__ hs,  // bf16x2 [N][64]
                                                   const int* __restrict__ row_ptr,
                                                   const int* __restrict__ col,
                                                   const float* __restrict__ dinv,
                                                   const float* __restrict__ bias,
                                                   void* __restrict__ outp, int N) {
    int i = blockIdx.x * 4 + (threadIdx.x >> 6);
    if (i >= N) return;
    int lane = threadIdx.x & 63;
    uint u = hs[(size_t)i * 64 + lane];  // self-loop
    float ax = bf16lo(u), ay = bf16hi(u);
    int s = row_ptr[i], e = row_ptr[i + 1];
    int k = s;
    for (; k + 4 <= e; k += 4) {
        int s0 = col[k], s1 = col[k + 1], s2 = col[k + 2], s3 = col[k + 3];
        uint u0 = hs[(size_t)s0 * 64 + lane];
        uint u1 = hs[(size_t)s1 * 64 + lane];
        uint u2 = hs[(size_t)s2 * 64 + lane];
        uint u3 = hs[(size_t)s3 * 64 + lane];
        ax += (bf16lo(u0) + bf16lo(u1)) + (bf16lo(u2) + bf16lo(u3));
        ay += (bf16hi(u0) + bf16hi(u1)) + (bf16hi(u2) + bf16hi(u3));
    }
    for (; k < e; ++k) {
        uint u0 = hs[(size_t)col[k] * 64 + lane];
        ax += bf16lo(u0);
        ay += bf16hi(u0);
    }
    float di = dinv[i];
    float2 bv = ((const float2*)bias)[lane];
    float ox = fmaxf(fmaf(di, ax, bv.x), 0.f);
    float oy = fmaxf(fmaf(di, ay, bv.y), 0.f);
    if (OUT_BF16) {
        uint p = ((uint)f2bf(oy) << 16) | (uint)f2bf(ox);
        ((uint*)outp)[(size_t)i * 64 + lane] = p;
    } else {
        ((float2*)outp)[(size_t)i * 64 + lane] = make_float2(ox, oy);
    }
}

// ---------------- launch ----------------
extern "C" void kernel_launch(void* const* d_in, const int* in_sizes, int n_in,
                              void* d_out, int out_size, void* d_ws, size_t ws_size,
                              hipStream_t stream) {
    const float* x = (const float*)d_in[0];
    const int* ei = (const int*)d_in[1];
    const float* W1 = (const float*)d_in[2];
    const float* b1 = (const float*)d_in[3];
    const float* W2 = (const float*)d_in[4];
    const float* b2 = (const float*)d_in[5];
    float* out = (float*)d_out;

    const int N = in_sizes[0] / NFEAT;  // 100000
    const int E = in_sizes[1] / 2;      // 1600000
    const int* src = ei;
    const int* dst = ei + E;

    char* w = (char*)d_ws;
    size_t off = 0;
    auto alloc = [&](size_t bytes) -> void* {
        void* p = w + off;
        off = (off + bytes + 511) & ~(size_t)511;
        return p;
    };
    ushort* hs = (ushort*)alloc((size_t)N * NFEAT * 2);  // bf16 scaled transform
    ushort* y1 = (ushort*)alloc((size_t)N * NFEAT * 2);  // bf16 layer-1 activations
    ushort* WT1 = (ushort*)alloc(128 * 128 * 2);
    ushort* WT2 = (ushort*)alloc(128 * 128 * 2);
    int* counts = (int*)alloc((size_t)N * 4);
    int* row_ptr = (int*)alloc((size_t)(N + 1) * 4);
    float* dinv = (float*)alloc((size_t)N * 4);
    int* col = (int*)alloc((size_t)E * 4);
    int* bsums = (int*)alloc(1024 * 4);
    (void)ws_size; (void)n_in; (void)out_size;

    const int nblkN = (N + 255) / 256;
    const int nblkE = (E + 255) / 256;
    const int nscan = (N + 1023) / 1024;

    k_prep_wt<<<2, 256, 0, stream>>>(W1, W2, WT1, WT2);
    k_zero_i32<<<nblkN, 256, 0, stream>>>(counts, N);
    k_count<<<nblkE, 256, 0, stream>>>(dst, counts, E);
    k_scan1<<<nscan, 256, 0, stream>>>(counts, row_ptr, bsums, N);
    k_scan2<<<1, 128, 0, stream>>>(bsums, nscan);
    k_scan3<<<nblkN, 256, 0, stream>>>(row_ptr, bsums, counts, dinv, N, E);
    k_fill<<<nblkE, 256, 0, stream>>>(src, dst, row_ptr, counts, col, E);

    const int gemmBlk = (N + 127) / 128;
    const int aggBlk = (N + 3) / 4;

    k_gemm_mfma<false><<<gemmBlk, 256, 0, stream>>>(x, WT1, dinv, hs, N);
    k_aggregate<true><<<aggBlk, 256, 0, stream>>>((const uint*)hs, row_ptr, col, dinv, b1, y1, N);
    k_gemm_mfma<true><<<gemmBlk, 256, 0, stream>>>(y1, WT2, dinv, hs, N);
    k_aggregate<false><<<aggBlk, 256, 0, stream>>>((const uint*)hs, row_ptr, col, dinv, b2, out, N);
}

// Round 3
// 346.553 us; speedup vs baseline: 1.7214x; 1.3864x over previous
//
#include <hip/hip_runtime.h>

// GCN 2-layer: h = relu(Ahat @ (x @ W) + b), twice.
// Round 3: replace scatter CSR fill (107 MB write amplification, 120 us) with
// bucketed counting sort: bucket = dst>>7 (128 nodes), dense LDS-staged writes.
// bf16 MFMA GEMM + bf16 gather aggregation unchanged from round 2.

#define NFEAT 128
#define BSH 7                 // bucket shift: 128 nodes per bucket
#define MAXNB 1024            // LDS histogram capacity (NB = ceil(N/128) = 782)
#define FILL_CAP 4096         // per-bucket LDS col capacity (mean 2048, sigma 45)

typedef __attribute__((ext_vector_type(8))) short s8v;  // 8 bf16 MFMA A/B frag
typedef __attribute__((ext_vector_type(4))) float f4v;  // MFMA C/D frag

// ---- bf16 helpers (rne) ----
__device__ inline ushort f2bf(float f) {
    union { float f; uint u; } x; x.f = f;
    uint u = x.u;
    return (ushort)((u + 0x7fffu + ((u >> 16) & 1u)) >> 16);
}
__device__ inline float bf16lo(uint u) { union { uint u; float f; } x; x.u = u << 16; return x.f; }
__device__ inline float bf16hi(uint u) { union { uint u; float f; } x; x.u = u & 0xffff0000u; return x.f; }

// ---------------- utility ----------------
__global__ __launch_bounds__(256) void k_zero_i32(int* __restrict__ p, int n) {
    int i = blockIdx.x * 256 + threadIdx.x;
    if (i < n) p[i] = 0;
}

// ---------------- bucket histogram: bcnt[b] = #edges with dst>>7 == b ----------------
__global__ __launch_bounds__(256) void k_bhist(const int* __restrict__ dst,
                                               int* __restrict__ bcnt, int E, int NB, int CH) {
    __shared__ int h[MAXNB];
    int t = threadIdx.x;
    for (int i = t; i < NB; i += 256) h[i] = 0;
    __syncthreads();
    int e0 = blockIdx.x * CH;
    int e1 = min(e0 + CH, E);
    for (int e = e0 + t; e < e1; e += 256) atomicAdd(&h[dst[e] >> BSH], 1);
    __syncthreads();
    for (int i = t; i < NB; i += 256)
        if (h[i]) atomicAdd(&bcnt[i], h[i]);
}

// ---------------- single-block exclusive scan of bucket counts ----------------
__global__ __launch_bounds__(256) void k_bscan(const int* __restrict__ bcnt,
                                               int* __restrict__ bbase,
                                               int* __restrict__ gcur,
                                               int* __restrict__ row_ptr,
                                               int NB, int N, int E) {
    __shared__ int sdata[256];
    int tid = threadIdx.x;
    int base = tid * 4;
    int v[4];
#pragma unroll
    for (int j = 0; j < 4; j++) v[j] = (base + j < NB) ? bcnt[base + j] : 0;
    int tsum = v[0] + v[1] + v[2] + v[3];
    sdata[tid] = tsum;
    __syncthreads();
    for (int off = 1; off < 256; off <<= 1) {
        int add = (tid >= off) ? sdata[tid - off] : 0;
        __syncthreads();
        sdata[tid] += add;
        __syncthreads();
    }
    int run = sdata[tid] - tsum;
#pragma unroll
    for (int j = 0; j < 4; j++) {
        if (base + j < NB) { bbase[base + j] = run; gcur[base + j] = run; }
        run += v[j];
    }
    if (tid == 0) { bbase[NB] = E; row_ptr[N] = E; }
}

// ---------------- bucketed scatter: ebuf[pos] = (src<<7)|dstlo, bucket-ordered ----
// Per-block LDS histogram -> one reservation atomic per (block,bucket) -> dense runs.
__global__ __launch_bounds__(256) void k_bscatter(const int* __restrict__ src,
                                                  const int* __restrict__ dst,
                                                  int* __restrict__ gcur,
                                                  uint* __restrict__ ebuf,
                                                  int E, int NB, int CH) {
    __shared__ int h[MAXNB];
    int t = threadIdx.x;
    for (int i = t; i < NB; i += 256) h[i] = 0;
    __syncthreads();
    int e0 = blockIdx.x * CH;
    int e1 = min(e0 + CH, E);
    for (int e = e0 + t; e < e1; e += 256) atomicAdd(&h[dst[e] >> BSH], 1);
    __syncthreads();
    for (int i = t; i < NB; i += 256) {
        int c = h[i];
        h[i] = c ? atomicAdd(&gcur[i], c) : 0;  // h[i] = this block's global cursor
    }
    __syncthreads();
    for (int e = e0 + t; e < e1; e += 256) {
        int d = dst[e];
        int b = d >> BSH;
        int p = atomicAdd(&h[b], 1);
        ebuf[p] = ((uint)src[e] << BSH) | (uint)(d & ((1 << BSH) - 1));  // N < 2^17
    }
}

// ---------------- per-bucket CSR finalize: row_ptr, dinv, sorted col ----------------
__global__ __launch_bounds__(256) void k_fill2(const uint* __restrict__ ebuf,
                                               const int* __restrict__ bbase,
                                               int* __restrict__ row_ptr,
                                               float* __restrict__ dinv,
                                               int* __restrict__ col, int N) {
    __shared__ int cnt[128];
    __shared__ int pre[128];
    __shared__ int colL[FILL_CAP];
    int b = blockIdx.x;
    int t = threadIdx.x;
    int gb = bbase[b], ge = bbase[b + 1];
    int m = ge - gb;
    if (t < 128) cnt[t] = 0;
    __syncthreads();
    for (int i = gb + t; i < ge; i += 256) atomicAdd(&cnt[ebuf[i] & 127], 1);
    __syncthreads();
    // exclusive scan of cnt[0..127] -> pre
    if (t < 128) pre[t] = cnt[t];
    __syncthreads();
    for (int off = 1; off < 128; off <<= 1) {
        int add = (t >= off && t < 128) ? pre[t - off] : 0;
        __syncthreads();
        if (t < 128) pre[t] += add;
        __syncthreads();
    }
    if (t < 128) {
        pre[t] -= cnt[t];  // exclusive
        int node = (b << BSH) + t;
        if (node < N) {
            row_ptr[node] = gb + pre[t];
            dinv[node] = rsqrtf((float)(cnt[t] + 1));
        }
    }
    __syncthreads();
    if (m <= FILL_CAP) {
        for (int i = gb + t; i < ge; i += 256) {
            uint p = ebuf[i];
            int pos = atomicAdd(&pre[p & 127], 1);
            colL[pos] = (int)(p >> BSH);
        }
        __syncthreads();
        for (int i = t; i < m; i += 256) col[gb + i] = colL[i];  // coalesced
    } else {  // overflow fallback (never for this input)
        for (int i = gb + t; i < ge; i += 256) {
            uint p = ebuf[i];
            int pos = atomicAdd(&pre[p & 127], 1);
            col[gb + pos] = (int)(p >> BSH);
        }
    }
}

// ---------------- W transpose + bf16 convert (once per call, 2 tiny blocks) ----------------
__global__ __launch_bounds__(256) void k_prep_wt(const float* __restrict__ W1,
                                                 const float* __restrict__ W2,
                                                 ushort* __restrict__ WT1,
                                                 ushort* __restrict__ WT2) {
    __shared__ float Ls[128][133];
    const float* W = blockIdx.x ? W2 : W1;
    ushort* WT = blockIdx.x ? WT2 : WT1;
    int t = threadIdx.x;
#pragma unroll
    for (int i = 0; i < 64; i++) {
        int idx = t + i * 256;
        Ls[idx >> 7][idx & 127] = W[idx];
    }
    __syncthreads();
#pragma unroll
    for (int i = 0; i < 8; i++) {
        int idx = t + i * 256;
        int n = idx >> 4;
        int k8 = (idx & 15) << 3;
        ushort o[8];
#pragma unroll
        for (int j = 0; j < 8; j++) o[j] = f2bf(Ls[k8 + j][n]);
        uint4 pk;
        __builtin_memcpy(&pk, o, 16);
        *(uint4*)&WT[n * 128 + k8] = pk;  // WT[n][k] row-major bf16
    }
}

// ---------------- MFMA GEMM: hs[m][n] = bf16( dinv[m] * sum_k A[m][k] W[k][n] ) ----
__device__ inline ushort* lds_chunk(ushort* base, int r, int c) {
    return base + r * 128 + ((c ^ (r & 15)) << 3);  // 16B-chunk XOR swizzle
}

template <bool ABF16>
__global__ __launch_bounds__(256) void k_gemm_mfma(const void* __restrict__ Ap,
                                                   const ushort* __restrict__ WT,
                                                   const float* __restrict__ dinv,
                                                   ushort* __restrict__ hs, int M) {
    __shared__ ushort As[128 * 128];
    __shared__ ushort Bs[128 * 128];
    int t = threadIdx.x;
    int m0 = blockIdx.x * 128;

    {
        const uint4* wt4 = (const uint4*)WT;
#pragma unroll
        for (int i = 0; i < 8; i++) {
            int idx = t + i * 256;
            int n = idx >> 4;
            int c = idx & 15;
            uint4 v = wt4[idx];
            *(uint4*)lds_chunk(Bs, n, c) = v;
        }
    }
    if (ABF16) {
        const ushort* A = (const ushort*)Ap;
#pragma unroll
        for (int i = 0; i < 8; i++) {
            int idx = t + i * 256;
            int r = idx >> 4;
            int c = idx & 15;
            int row = m0 + r;
            uint4 v = make_uint4(0, 0, 0, 0);
            if (row < M) v = *(const uint4*)(A + (size_t)row * NFEAT + (c << 3));
            *(uint4*)lds_chunk(As, r, c) = v;
        }
    } else {
        const float* A = (const float*)Ap;
#pragma unroll
        for (int i = 0; i < 16; i++) {
            int idx = t + i * 256;
            int r = idx >> 5;
            int t5 = idx & 31;
            int c = t5 >> 1;
            int h = t5 & 1;
            int row = m0 + r;
            float4 v = make_float4(0.f, 0.f, 0.f, 0.f);
            if (row < M) v = *(const float4*)(A + (size_t)row * NFEAT + t5 * 4);
            ushort o[4] = {f2bf(v.x), f2bf(v.y), f2bf(v.z), f2bf(v.w)};
            uint2 pk;
            __builtin_memcpy(&pk, o, 8);
            *(uint2*)(lds_chunk(As, r, c) + h * 4) = pk;
        }
    }
    __syncthreads();

    int w = t >> 6, l = t & 63;
    int q = l >> 4, ln = l & 15;
    f4v acc[2][8];
#pragma unroll
    for (int mt = 0; mt < 2; mt++)
#pragma unroll
        for (int nt = 0; nt < 8; nt++) acc[mt][nt] = (f4v){0.f, 0.f, 0.f, 0.f};

#pragma unroll
    for (int ks = 0; ks < 4; ks++) {
        int c = ks * 4 + q;
        s8v a0 = *(s8v*)lds_chunk(As, w * 32 + ln, c);
        s8v a1 = *(s8v*)lds_chunk(As, w * 32 + 16 + ln, c);
#pragma unroll
        for (int nt = 0; nt < 8; nt++) {
            s8v bb = *(s8v*)lds_chunk(Bs, nt * 16 + ln, c);
            acc[0][nt] = __builtin_amdgcn_mfma_f32_16x16x32_bf16(a0, bb, acc[0][nt], 0, 0, 0);
            acc[1][nt] = __builtin_amdgcn_mfma_f32_16x16x32_bf16(a1, bb, acc[1][nt], 0, 0, 0);
        }
    }

#pragma unroll
    for (int mt = 0; mt < 2; mt++) {
#pragma unroll
        for (int r = 0; r < 4; r++) {
            int grow = m0 + w * 32 + mt * 16 + q * 4 + r;
            if (grow < M) {
                float d = dinv[grow];
#pragma unroll
                for (int nt = 0; nt < 8; nt++) {
                    hs[(size_t)grow * NFEAT + nt * 16 + ln] = f2bf(acc[mt][nt][r] * d);
                }
            }
        }
    }
}

// ---------------- Aggregation: wave per node, bf16 messages, fp32 accumulate ----
template <bool OUT_BF16>
__global__ __launch_bounds__(256) void k_aggregate(const uint* __restrict__ hs,
                                                   const int* __restrict__ row_ptr,
                                                   const int* __restrict__ col,
                                                   const float* __restrict__ dinv,
                                                   const float* __restrict__ bias,
                                                   void* __restrict__ outp, int N) {
    int i = blockIdx.x * 4 + (threadIdx.x >> 6);
    if (i >= N) return;
    int lane = threadIdx.x & 63;
    uint u = hs[(size_t)i * 64 + lane];  // self-loop
    float ax = bf16lo(u), ay = bf16hi(u);
    int s = row_ptr[i], e = row_ptr[i + 1];
    int k = s;
    for (; k + 4 <= e; k += 4) {
        int s0 = col[k], s1 = col[k + 1], s2 = col[k + 2], s3 = col[k + 3];
        uint u0 = hs[(size_t)s0 * 64 + lane];
        uint u1 = hs[(size_t)s1 * 64 + lane];
        uint u2 = hs[(size_t)s2 * 64 + lane];
        uint u3 = hs[(size_t)s3 * 64 + lane];
        ax += (bf16lo(u0) + bf16lo(u1)) + (bf16lo(u2) + bf16lo(u3));
        ay += (bf16hi(u0) + bf16hi(u1)) + (bf16hi(u2) + bf16hi(u3));
    }
    for (; k < e; ++k) {
        uint u0 = hs[(size_t)col[k] * 64 + lane];
        ax += bf16lo(u0);
        ay += bf16hi(u0);
    }
    float di = dinv[i];
    float2 bv = ((const float2*)bias)[lane];
    float ox = fmaxf(fmaf(di, ax, bv.x), 0.f);
    float oy = fmaxf(fmaf(di, ay, bv.y), 0.f);
    if (OUT_BF16) {
        uint p = ((uint)f2bf(oy) << 16) | (uint)f2bf(ox);
        ((uint*)outp)[(size_t)i * 64 + lane] = p;
    } else {
        ((float2*)outp)[(size_t)i * 64 + lane] = make_float2(ox, oy);
    }
}

// ---------------- launch ----------------
extern "C" void kernel_launch(void* const* d_in, const int* in_sizes, int n_in,
                              void* d_out, int out_size, void* d_ws, size_t ws_size,
                              hipStream_t stream) {
    const float* x = (const float*)d_in[0];
    const int* ei = (const int*)d_in[1];
    const float* W1 = (const float*)d_in[2];
    const float* b1 = (const float*)d_in[3];
    const float* W2 = (const float*)d_in[4];
    const float* b2 = (const float*)d_in[5];
    float* out = (float*)d_out;

    const int N = in_sizes[0] / NFEAT;  // 100000  (must be < 2^17 for 4B edge pack)
    const int E = in_sizes[1] / 2;      // 1600000
    const int* src = ei;
    const int* dst = ei + E;
    const int NB = (N + (1 << BSH) - 1) >> BSH;  // 782 buckets

    char* w = (char*)d_ws;
    size_t off = 0;
    auto alloc = [&](size_t bytes) -> void* {
        void* p = w + off;
        off = (off + bytes + 511) & ~(size_t)511;
        return p;
    };
    ushort* hs = (ushort*)alloc((size_t)N * NFEAT * 2);
    ushort* y1 = (ushort*)alloc((size_t)N * NFEAT * 2);
    ushort* WT1 = (ushort*)alloc(128 * 128 * 2);
    ushort* WT2 = (ushort*)alloc(128 * 128 * 2);
    int* row_ptr = (int*)alloc((size_t)(N + 1) * 4);
    float* dinv = (float*)alloc((size_t)N * 4);
    int* col = (int*)alloc((size_t)E * 4);
    uint* ebuf = (uint*)alloc((size_t)E * 4);
    int* bcnt = (int*)alloc((size_t)MAXNB * 4);
    int* bbase = (int*)alloc((size_t)(MAXNB + 1) * 4);
    int* gcur = (int*)alloc((size_t)MAXNB * 4);
    (void)ws_size; (void)n_in; (void)out_size;

    const int CH = 8192;
    const int chBlk = (E + CH - 1) / CH;  // 196

    k_prep_wt<<<2, 256, 0, stream>>>(W1, W2, WT1, WT2);
    k_zero_i32<<<(NB + 255) / 256, 256, 0, stream>>>(bcnt, NB);
    k_bhist<<<chBlk, 256, 0, stream>>>(dst, bcnt, E, NB, CH);
    k_bscan<<<1, 256, 0, stream>>>(bcnt, bbase, gcur, row_ptr, NB, N, E);
    k_bscatter<<<chBlk, 256, 0, stream>>>(src, dst, gcur, ebuf, E, NB, CH);
    k_fill2<<<NB, 256, 0, stream>>>(ebuf, bbase, row_ptr, dinv, col, N);

    const int gemmBlk = (N + 127) / 128;
    const int aggBlk = (N + 3) / 4;

    k_gemm_mfma<false><<<gemmBlk, 256, 0, stream>>>(x, WT1, dinv, hs, N);
    k_aggregate<true><<<aggBlk, 256, 0, stream>>>((const uint*)hs, row_ptr, col, dinv, b1, y1, N);
    k_gemm_mfma<true><<<gemmBlk, 256, 0, stream>>>(y1, WT2, dinv, hs, N);
    k_aggregate<false><<<aggBlk, 256, 0, stream>>>((const uint*)hs, row_ptr, col, dinv, b2, out, N);
}

// Round 4
// 323.102 us; speedup vs baseline: 1.8463x; 1.0726x over previous
//
#include <hip/hip_runtime.h>

// GCN 2-layer: h = relu(Ahat @ (x @ W) + b), twice.
// Round 4: aggregate gathers 4 edge-rows per dwordx4 instruction (16-lane groups),
// CSR build compacted to 2 kernels (fixed-capacity bucket scatter + in-block base scan).
// 7 launches total: prep, bscatter, fill2, gemm, agg, gemm, agg.

#define NFEAT 128
#define BSH 7                  // 128 nodes per bucket
#define MAXNB 1024             // >= NB = ceil(N/128) = 782
#define BCAP 4096              // per-bucket ebuf capacity (mean 2046, sigma 45)

typedef __attribute__((ext_vector_type(8))) short s8v;  // 8 bf16 MFMA A/B frag
typedef __attribute__((ext_vector_type(4))) float f4v;  // MFMA C/D frag

// ---- bf16 helpers (rne) ----
__device__ inline ushort f2bf(float f) {
    union { float f; uint u; } x; x.f = f;
    uint u = x.u;
    return (ushort)((u + 0x7fffu + ((u >> 16) & 1u)) >> 16);
}
__device__ inline float bf16lo(uint u) { union { uint u; float f; } x; x.u = u << 16; return x.f; }
__device__ inline float bf16hi(uint u) { union { uint u; float f; } x; x.u = u & 0xffff0000u; return x.f; }

__device__ inline void upadd(uint4 v, float* a) {
    a[0] += bf16lo(v.x); a[1] += bf16hi(v.x);
    a[2] += bf16lo(v.y); a[3] += bf16hi(v.y);
    a[4] += bf16lo(v.z); a[5] += bf16hi(v.z);
    a[6] += bf16lo(v.w); a[7] += bf16hi(v.w);
}

// ---------------- prep: W->WT bf16 (blocks 0,1) + zero gcnt & hs dummy row (block 2) ----
__global__ __launch_bounds__(256) void k_prep(const float* __restrict__ W1,
                                              const float* __restrict__ W2,
                                              ushort* __restrict__ WT1,
                                              ushort* __restrict__ WT2,
                                              int* __restrict__ gcnt,
                                              ushort* __restrict__ hs, int N) {
    int t = threadIdx.x;
    if (blockIdx.x == 2) {
        for (int i = t; i < MAXNB; i += 256) gcnt[i] = 0;
        if (t < 64) ((uint*)(hs + (size_t)N * NFEAT))[t] = 0;  // dummy zero row N
        return;
    }
    __shared__ float Ls[128][133];
    const float* W = blockIdx.x ? W2 : W1;
    ushort* WT = blockIdx.x ? WT2 : WT1;
#pragma unroll
    for (int i = 0; i < 64; i++) {
        int idx = t + i * 256;
        Ls[idx >> 7][idx & 127] = W[idx];
    }
    __syncthreads();
#pragma unroll
    for (int i = 0; i < 8; i++) {
        int idx = t + i * 256;
        int n = idx >> 4;
        int k8 = (idx & 15) << 3;
        ushort o[8];
#pragma unroll
        for (int j = 0; j < 8; j++) o[j] = f2bf(Ls[k8 + j][n]);
        uint4 pk;
        __builtin_memcpy(&pk, o, 16);
        *(uint4*)&WT[n * 128 + k8] = pk;  // WT[n][k] row-major bf16
    }
}

// ---------------- bucketed scatter into fixed-capacity segments ----------------
__global__ __launch_bounds__(256) void k_bscatter(const int* __restrict__ src,
                                                  const int* __restrict__ dst,
                                                  int* __restrict__ gcnt,
                                                  uint* __restrict__ ebuf,
                                                  int E, int NB, int CH) {
    __shared__ int h[MAXNB];
    int t = threadIdx.x;
    for (int i = t; i < NB; i += 256) h[i] = 0;
    __syncthreads();
    int e0 = blockIdx.x * CH;
    int e1 = min(e0 + CH, E);
    for (int e = e0 + t; e < e1; e += 256) atomicAdd(&h[dst[e] >> BSH], 1);
    __syncthreads();
    for (int i = t; i < NB; i += 256) {
        int c = h[i];
        h[i] = c ? (i * BCAP + atomicAdd(&gcnt[i], c)) : 0;  // global cursor
    }
    __syncthreads();
    for (int e = e0 + t; e < e1; e += 256) {
        int d = dst[e];
        int b = d >> BSH;
        int p = atomicAdd(&h[b], 1);
        if (p < (b + 1) * BCAP)  // capacity guard (statistically never taken)
            ebuf[p] = ((uint)src[e] << BSH) | (uint)(d & ((1 << BSH) - 1));
    }
}

// ---------------- per-bucket CSR finalize (base scan in-block) ----------------
__global__ __launch_bounds__(256) void k_fill2(const uint* __restrict__ ebuf,
                                               const int* __restrict__ gcnt,
                                               int* __restrict__ row_ptr,
                                               float* __restrict__ dinv,
                                               int* __restrict__ col,
                                               int N, int E, int NB) {
    __shared__ int cnt[128];
    __shared__ int pre[128];
    __shared__ int sred[256];
    __shared__ int colL[BCAP];
    int b = blockIdx.x;
    int t = threadIdx.x;
    // global base gb = sum_{j<b} gcnt[j]
    int part = 0;
    for (int j = t; j < b; j += 256) part += gcnt[j];
    sred[t] = part;
    __syncthreads();
    for (int off = 128; off >= 1; off >>= 1) {
        if (t < off) sred[t] += sred[t + off];
        __syncthreads();
    }
    int gb = sred[0];
    int m = min(gcnt[b], BCAP);
    if (t < 128) cnt[t] = 0;
    __syncthreads();
    const uint* eb = ebuf + (size_t)b * BCAP;
    for (int i = t; i < m; i += 256) atomicAdd(&cnt[eb[i] & 127], 1);
    __syncthreads();
    if (t < 128) pre[t] = cnt[t];
    __syncthreads();
    for (int off = 1; off < 128; off <<= 1) {
        int add = (t >= off && t < 128) ? pre[t - off] : 0;
        __syncthreads();
        if (t < 128) pre[t] += add;
        __syncthreads();
    }
    if (t < 128) {
        pre[t] -= cnt[t];  // exclusive
        int node = (b << BSH) + t;
        if (node < N) {
            row_ptr[node] = gb + pre[t];
            dinv[node] = rsqrtf((float)(cnt[t] + 1));
        }
    }
    __syncthreads();
    for (int i = t; i < m; i += 256) {
        uint p = eb[i];
        int pos = atomicAdd(&pre[p & 127], 1);
        colL[pos] = (int)(p >> BSH);
    }
    __syncthreads();
    for (int i = t; i < m; i += 256) col[gb + i] = colL[i];  // coalesced
    if (b == NB - 1 && t == 0) row_ptr[N] = E;
}

// ---------------- MFMA GEMM: hs[m][n] = bf16( dinv[m] * sum_k A[m][k] W[k][n] ) ----
__device__ inline ushort* lds_chunk(ushort* base, int r, int c) {
    return base + r * 128 + ((c ^ (r & 15)) << 3);  // 16B-chunk XOR swizzle
}

template <bool ABF16>
__global__ __launch_bounds__(256) void k_gemm_mfma(const void* __restrict__ Ap,
                                                   const ushort* __restrict__ WT,
                                                   const float* __restrict__ dinv,
                                                   ushort* __restrict__ hs, int M) {
    __shared__ ushort As[128 * 128];
    __shared__ ushort Bs[128 * 128];
    int t = threadIdx.x;
    int m0 = blockIdx.x * 128;

    {
        const uint4* wt4 = (const uint4*)WT;
#pragma unroll
        for (int i = 0; i < 8; i++) {
            int idx = t + i * 256;
            int n = idx >> 4;
            int c = idx & 15;
            uint4 v = wt4[idx];
            *(uint4*)lds_chunk(Bs, n, c) = v;
        }
    }
    if (ABF16) {
        const ushort* A = (const ushort*)Ap;
#pragma unroll
        for (int i = 0; i < 8; i++) {
            int idx = t + i * 256;
            int r = idx >> 4;
            int c = idx & 15;
            int row = m0 + r;
            uint4 v = make_uint4(0, 0, 0, 0);
            if (row < M) v = *(const uint4*)(A + (size_t)row * NFEAT + (c << 3));
            *(uint4*)lds_chunk(As, r, c) = v;
        }
    } else {
        const float* A = (const float*)Ap;
#pragma unroll
        for (int i = 0; i < 16; i++) {
            int idx = t + i * 256;
            int r = idx >> 5;
            int t5 = idx & 31;
            int c = t5 >> 1;
            int h = t5 & 1;
            int row = m0 + r;
            float4 v = make_float4(0.f, 0.f, 0.f, 0.f);
            if (row < M) v = *(const float4*)(A + (size_t)row * NFEAT + t5 * 4);
            ushort o[4] = {f2bf(v.x), f2bf(v.y), f2bf(v.z), f2bf(v.w)};
            uint2 pk;
            __builtin_memcpy(&pk, o, 8);
            *(uint2*)(lds_chunk(As, r, c) + h * 4) = pk;
        }
    }
    __syncthreads();

    int w = t >> 6, l = t & 63;
    int q = l >> 4, ln = l & 15;
    f4v acc[2][8];
#pragma unroll
    for (int mt = 0; mt < 2; mt++)
#pragma unroll
        for (int nt = 0; nt < 8; nt++) acc[mt][nt] = (f4v){0.f, 0.f, 0.f, 0.f};

#pragma unroll
    for (int ks = 0; ks < 4; ks++) {
        int c = ks * 4 + q;
        s8v a0 = *(s8v*)lds_chunk(As, w * 32 + ln, c);
        s8v a1 = *(s8v*)lds_chunk(As, w * 32 + 16 + ln, c);
#pragma unroll
        for (int nt = 0; nt < 8; nt++) {
            s8v bb = *(s8v*)lds_chunk(Bs, nt * 16 + ln, c);
            acc[0][nt] = __builtin_amdgcn_mfma_f32_16x16x32_bf16(a0, bb, acc[0][nt], 0, 0, 0);
            acc[1][nt] = __builtin_amdgcn_mfma_f32_16x16x32_bf16(a1, bb, acc[1][nt], 0, 0, 0);
        }
    }

#pragma unroll
    for (int mt = 0; mt < 2; mt++) {
#pragma unroll
        for (int r = 0; r < 4; r++) {
            int grow = m0 + w * 32 + mt * 16 + q * 4 + r;
            if (grow < M) {
                float d = dinv[grow];
#pragma unroll
                for (int nt = 0; nt < 8; nt++) {
                    hs[(size_t)grow * NFEAT + nt * 16 + ln] = f2bf(acc[mt][nt][r] * d);
                }
            }
        }
    }
}

// ---------------- Aggregation: wave per node, 4 edges per dwordx4 gather ----
// lane = (group g = lane>>4) x (sub = lane&15); group g gathers edge k+g's row,
// lane reads 16B = feats [8*sub, 8*sub+8). Cross-group reduce via shfl_xor 16/32.
template <bool OUT_BF16>
__global__ __launch_bounds__(256) void k_aggregate(const uint4* __restrict__ hs4,
                                                   const int* __restrict__ row_ptr,
                                                   const int* __restrict__ col,
                                                   const float* __restrict__ dinv,
                                                   const float* __restrict__ bias,
                                                   void* __restrict__ outp, int N) {
    int i = blockIdx.x * 4 + (threadIdx.x >> 6);
    if (i >= N) return;
    int lane = threadIdx.x & 63;
    int g = lane >> 4, sub = lane & 15;
    float a[8];
#pragma unroll
    for (int j = 0; j < 8; j++) a[j] = 0.f;
    if (g == 0) upadd(hs4[(size_t)i * 16 + sub], a);  // self-loop (group 0 only)
    int s = row_ptr[i], e = row_ptr[i + 1];
    int k = s;
    for (; k + 16 <= e; k += 16) {
        int c0 = col[k + g];
        int c1 = col[k + 4 + g];
        int c2 = col[k + 8 + g];
        int c3 = col[k + 12 + g];
        uint4 v0 = hs4[(size_t)c0 * 16 + sub];
        uint4 v1 = hs4[(size_t)c1 * 16 + sub];
        uint4 v2 = hs4[(size_t)c2 * 16 + sub];
        uint4 v3 = hs4[(size_t)c3 * 16 + sub];
        upadd(v0, a); upadd(v1, a); upadd(v2, a); upadd(v3, a);
    }
    for (; k < e; k += 4) {  // masked batches; OOB groups read zero row N
        int idx = k + g;
        int c = N;
        if (idx < e) c = col[idx];
        upadd(hs4[(size_t)c * 16 + sub], a);
    }
#pragma unroll
    for (int j = 0; j < 8; j++) {
        a[j] += __shfl_xor(a[j], 16, 64);
        a[j] += __shfl_xor(a[j], 32, 64);
    }
    if (lane < 16) {
        float di = dinv[i];
        const float4* b4 = (const float4*)bias;
        float4 b0 = b4[sub * 2], b1 = b4[sub * 2 + 1];
        float r[8];
        r[0] = fmaxf(fmaf(di, a[0], b0.x), 0.f);
        r[1] = fmaxf(fmaf(di, a[1], b0.y), 0.f);
        r[2] = fmaxf(fmaf(di, a[2], b0.z), 0.f);
        r[3] = fmaxf(fmaf(di, a[3], b0.w), 0.f);
        r[4] = fmaxf(fmaf(di, a[4], b1.x), 0.f);
        r[5] = fmaxf(fmaf(di, a[5], b1.y), 0.f);
        r[6] = fmaxf(fmaf(di, a[6], b1.z), 0.f);
        r[7] = fmaxf(fmaf(di, a[7], b1.w), 0.f);
        if (OUT_BF16) {
            ushort o[8];
#pragma unroll
            for (int j = 0; j < 8; j++) o[j] = f2bf(r[j]);
            uint4 pk;
            __builtin_memcpy(&pk, o, 16);
            ((uint4*)outp)[(size_t)i * 16 + sub] = pk;
        } else {
            float* orow = (float*)outp + (size_t)i * NFEAT + sub * 8;
            *(float4*)orow = make_float4(r[0], r[1], r[2], r[3]);
            *(float4*)(orow + 4) = make_float4(r[4], r[5], r[6], r[7]);
        }
    }
}

// ---------------- launch ----------------
extern "C" void kernel_launch(void* const* d_in, const int* in_sizes, int n_in,
                              void* d_out, int out_size, void* d_ws, size_t ws_size,
                              hipStream_t stream) {
    const float* x = (const float*)d_in[0];
    const int* ei = (const int*)d_in[1];
    const float* W1 = (const float*)d_in[2];
    const float* b1 = (const float*)d_in[3];
    const float* W2 = (const float*)d_in[4];
    const float* b2 = (const float*)d_in[5];
    float* out = (float*)d_out;

    const int N = in_sizes[0] / NFEAT;  // 100000  (< 2^17 for 4B edge pack)
    const int E = in_sizes[1] / 2;      // 1600000
    const int* src = ei;
    const int* dst = ei + E;
    const int NB = (N + (1 << BSH) - 1) >> BSH;  // 782

    char* w = (char*)d_ws;
    size_t off = 0;
    auto alloc = [&](size_t bytes) -> void* {
        void* p = w + off;
        off = (off + bytes + 511) & ~(size_t)511;
        return p;
    };
    ushort* hs = (ushort*)alloc((size_t)(N + 1) * NFEAT * 2);  // +1 dummy zero row
    ushort* y1 = (ushort*)alloc((size_t)N * NFEAT * 2);
    ushort* WT1 = (ushort*)alloc(128 * 128 * 2);
    ushort* WT2 = (ushort*)alloc(128 * 128 * 2);
    int* row_ptr = (int*)alloc((size_t)(N + 1) * 4);
    float* dinv = (float*)alloc((size_t)N * 4);
    int* col = (int*)alloc((size_t)E * 4);
    uint* ebuf = (uint*)alloc((size_t)NB * BCAP * 4);  // 12.8 MB
    int* gcnt = (int*)alloc((size_t)MAXNB * 4);
    (void)ws_size; (void)n_in; (void)out_size;

    const int CH = 8192;
    const int chBlk = (E + CH - 1) / CH;  // 196

    k_prep<<<3, 256, 0, stream>>>(W1, W2, WT1, WT2, gcnt, hs, N);
    k_bscatter<<<chBlk, 256, 0, stream>>>(src, dst, gcnt, ebuf, E, NB, CH);
    k_fill2<<<NB, 256, 0, stream>>>(ebuf, gcnt, row_ptr, dinv, col, N, E, NB);

    const int gemmBlk = (N + 127) / 128;
    const int aggBlk = (N + 3) / 4;

    k_gemm_mfma<false><<<gemmBlk, 256, 0, stream>>>(x, WT1, dinv, hs, N);
    k_aggregate<true><<<aggBlk, 256, 0, stream>>>((const uint4*)hs, row_ptr, col, dinv, b1, y1, N);
    k_gemm_mfma<true><<<gemmBlk, 256, 0, stream>>>(y1, WT2, dinv, hs, N);
    k_aggregate<false><<<aggBlk, 256, 0, stream>>>((const uint4*)hs, row_ptr, col, dinv, b2, out, N);
}